// Round 1
// baseline (2919.904 us; speedup 1.0000x reference)
//
#include <hip/hip_runtime.h>
#include <cstddef>

// ---------------------------------------------------------------------------
// RQ-VAE forward: 4 scalar losses.
//   H1 = gelu(x@eW1+eb1); Z = H1@eW2+eb2; R = Z
//   3x VQ stages: idx=argmin||r-c||^2, loss_s = 1.25*mean((r-q)^2), r -= q
//   output == Z - R_final (sum of q telescopes)
//   H2 = gelu((Z-R)@dW1+db1); recon = mean((H2@dW2+db2 - x)^2)
// All fp32 this round (correctness baseline; no fp32 MFMA on CDNA4).
// ---------------------------------------------------------------------------

#define TILE 128
#define BK   16
#define TM   8
#define TN   8
// 256 threads = 16x16 groups of 8x8 microtiles

__device__ __forceinline__ float gelu_exact(float v) {
    return 0.5f * v * (1.0f + erff(v * 0.7071067811865475f));
}

// EPI: 0 = gelu+store, 1 = store to two buffers (no gelu... wait, bias only),
//      2 = recon loss (no store)
// AMINUS: A value = A[i] - A2[i]  (used for output = Z - R)
template <int EPI, bool AMINUS>
__global__ __launch_bounds__(256)
void gemm_f32(const float* __restrict__ A, const float* __restrict__ A2,
              const float* __restrict__ B, const float* __restrict__ bias,
              float* __restrict__ Cout, float* __restrict__ Cout2,
              const float* __restrict__ X, float* __restrict__ lossOut,
              int N, int K, float lossScale)
{
    __shared__ float As[BK][TILE + 4];
    __shared__ float Bs[BK][TILE + 4];

    const int tid  = threadIdx.x;
    const int brow = blockIdx.y * TILE;
    const int bcol = blockIdx.x * TILE;
    const int tm0  = (tid >> 4) * TM;
    const int tn0  = (tid & 15) * TN;

    float acc[TM][TN];
#pragma unroll
    for (int m = 0; m < TM; ++m)
#pragma unroll
        for (int n = 0; n < TN; ++n) acc[m][n] = 0.f;

    const int ai = tid >> 2;        // 0..63  (row within A tile, +64 second pass)
    const int aj = (tid & 3) * 4;   // 0,4,8,12 (k offset)
    const int bi = tid >> 4;        // 0..15  (k row of B tile)
    const int bj = (tid & 15) * 8;  // 0..120 (col offset)

    for (int k0 = 0; k0 < K; k0 += BK) {
#pragma unroll
        for (int p = 0; p < 2; ++p) {
            const int i = ai + p * 64;
            float4 v = *(const float4*)&A[(size_t)(brow + i) * K + k0 + aj];
            if (AMINUS) {
                float4 w = *(const float4*)&A2[(size_t)(brow + i) * K + k0 + aj];
                v.x -= w.x; v.y -= w.y; v.z -= w.z; v.w -= w.w;
            }
            As[aj + 0][i] = v.x; As[aj + 1][i] = v.y;
            As[aj + 2][i] = v.z; As[aj + 3][i] = v.w;
        }
        {
            const float* bp = &B[(size_t)(k0 + bi) * N + bcol + bj];
            float4 v0 = *(const float4*)bp;
            float4 v1 = *(const float4*)(bp + 4);
            *(float4*)&Bs[bi][bj]     = v0;
            *(float4*)&Bs[bi][bj + 4] = v1;
        }
        __syncthreads();
#pragma unroll
        for (int kk = 0; kk < BK; ++kk) {
            float a[TM], b[TN];
#pragma unroll
            for (int m = 0; m < TM; ++m) a[m] = As[kk][tm0 + m];
#pragma unroll
            for (int n = 0; n < TN; ++n) b[n] = Bs[kk][tn0 + n];
#pragma unroll
            for (int m = 0; m < TM; ++m)
#pragma unroll
                for (int n = 0; n < TN; ++n)
                    acc[m][n] = fmaf(a[m], b[n], acc[m][n]);
        }
        __syncthreads();
    }

    float bv[TN];
#pragma unroll
    for (int n = 0; n < TN; ++n) bv[n] = bias[bcol + tn0 + n];

    if (EPI == 0) {
#pragma unroll
        for (int m = 0; m < TM; ++m) {
            float t[TN];
#pragma unroll
            for (int n = 0; n < TN; ++n) t[n] = gelu_exact(acc[m][n] + bv[n]);
            float* row = &Cout[(size_t)(brow + tm0 + m) * N + bcol + tn0];
            *(float4*)row       = make_float4(t[0], t[1], t[2], t[3]);
            *(float4*)(row + 4) = make_float4(t[4], t[5], t[6], t[7]);
        }
    } else if (EPI == 1) {
#pragma unroll
        for (int m = 0; m < TM; ++m) {
            float t[TN];
#pragma unroll
            for (int n = 0; n < TN; ++n) t[n] = acc[m][n] + bv[n];
            const size_t off = (size_t)(brow + tm0 + m) * N + bcol + tn0;
            *(float4*)&Cout[off]      = make_float4(t[0], t[1], t[2], t[3]);
            *(float4*)&Cout[off + 4]  = make_float4(t[4], t[5], t[6], t[7]);
            *(float4*)&Cout2[off]     = make_float4(t[0], t[1], t[2], t[3]);
            *(float4*)&Cout2[off + 4] = make_float4(t[4], t[5], t[6], t[7]);
        }
    } else {
        float partial = 0.f;
#pragma unroll
        for (int m = 0; m < TM; ++m) {
            const size_t off = (size_t)(brow + tm0 + m) * N + bcol + tn0;
#pragma unroll
            for (int n = 0; n < TN; ++n) {
                float o = acc[m][n] + bv[n];
                float d = o - X[off + n];
                partial = fmaf(d, d, partial);
            }
        }
        // block reduce via As scratch (all threads past last barrier)
        float* red = &As[0][0];
        red[tid] = partial;
        __syncthreads();
        for (int s = 128; s > 0; s >>= 1) {
            if (tid < s) red[tid] += red[tid + s];
            __syncthreads();
        }
        if (tid == 0) atomicAdd(lossOut, red[0] * lossScale);
    }
}

// ---------------------------------------------------------------------------
// codebook squared norms
__global__ void cnorm_kernel(const float* __restrict__ C, float* __restrict__ out)
{
    const int code = blockIdx.x;
    const int lane = threadIdx.x; // 64
    const float* row = &C[(size_t)code * 256];
    float s = 0.f;
#pragma unroll
    for (int d = lane; d < 256; d += 64) { float v = row[d]; s = fmaf(v, v, s); }
#pragma unroll
    for (int off = 32; off > 0; off >>= 1) s += __shfl_down(s, off);
    if (lane == 0) out[code] = s;
}

// ---------------------------------------------------------------------------
// VQ: each block owns 128 rows of R, runs all 3 stages privately.
// argmin over codes of (||c||^2 - 2 r.c); then r -= q, loss += 1.25*mean.
__global__ __launch_bounds__(256)
void vq_kernel(float* __restrict__ R,
               const float* __restrict__ C0, const float* __restrict__ C1,
               const float* __restrict__ C2, const float* __restrict__ cnorm,
               float* __restrict__ lossOut)
{
    __shared__ float Rs[BK][TILE + 4];
    __shared__ float Cs[BK][TILE + 4];
    __shared__ float redv[128][16];
    __shared__ int   redi[128][16];
    __shared__ int   idxs[128];

    const int tid  = threadIdx.x;
    const int brow = blockIdx.x * TILE;
    const int tm0  = (tid >> 4) * TM;
    const int tn0  = (tid & 15) * TN;

    const int ai = tid >> 2;
    const int aj = (tid & 3) * 4;

    const float* Cb[3]   = {C0, C1, C2};
    const int ncodes[3]  = {1024, 512, 256};
    const int coff[3]    = {0, 1024, 1536};
    const float lscale   = 1.25f / (65536.0f * 256.0f);

    for (int stage = 0; stage < 3; ++stage) {
        const float* C = Cb[stage];
        float best[TM];
        int   bidx[TM];
#pragma unroll
        for (int m = 0; m < TM; ++m) { best[m] = 3.0e38f; bidx[m] = 0; }

        for (int ct = 0; ct < ncodes[stage]; ct += TILE) {
            float acc[TM][TN];
#pragma unroll
            for (int m = 0; m < TM; ++m)
#pragma unroll
                for (int n = 0; n < TN; ++n) acc[m][n] = 0.f;

            for (int k0 = 0; k0 < 256; k0 += BK) {
#pragma unroll
                for (int p = 0; p < 2; ++p) {
                    const int i = ai + p * 64;
                    float4 v = *(const float4*)&R[(size_t)(brow + i) * 256 + k0 + aj];
                    Rs[aj + 0][i] = v.x; Rs[aj + 1][i] = v.y;
                    Rs[aj + 2][i] = v.z; Rs[aj + 3][i] = v.w;
                }
#pragma unroll
                for (int p = 0; p < 2; ++p) {
                    const int n = ai + p * 64;
                    float4 v = *(const float4*)&C[(size_t)(ct + n) * 256 + k0 + aj];
                    Cs[aj + 0][n] = v.x; Cs[aj + 1][n] = v.y;
                    Cs[aj + 2][n] = v.z; Cs[aj + 3][n] = v.w;
                }
                __syncthreads();
#pragma unroll
                for (int kk = 0; kk < BK; ++kk) {
                    float a[TM], b[TN];
#pragma unroll
                    for (int m = 0; m < TM; ++m) a[m] = Rs[kk][tm0 + m];
#pragma unroll
                    for (int n = 0; n < TN; ++n) b[n] = Cs[kk][tn0 + n];
#pragma unroll
                    for (int m = 0; m < TM; ++m)
#pragma unroll
                        for (int n = 0; n < TN; ++n)
                            acc[m][n] = fmaf(a[m], b[n], acc[m][n]);
                }
                __syncthreads();
            }
#pragma unroll
            for (int n = 0; n < TN; ++n) {
                const int code = ct + tn0 + n;
                const float cn = cnorm[coff[stage] + code];
#pragma unroll
                for (int m = 0; m < TM; ++m) {
                    float s = fmaf(-2.0f, acc[m][n], cn);
                    if (s < best[m]) { best[m] = s; bidx[m] = code; }
                }
            }
        }
        // cross-thread argmin per row (16 col-groups per row)
#pragma unroll
        for (int m = 0; m < TM; ++m) {
            redv[tm0 + m][tid & 15] = best[m];
            redi[tm0 + m][tid & 15] = bidx[m];
        }
        __syncthreads();
        if (tid < 128) {
            float bv = redv[tid][0]; int bi2 = redi[tid][0];
#pragma unroll
            for (int g = 1; g < 16; ++g) {
                float v = redv[tid][g]; int i2 = redi[tid][g];
                if (v < bv || (v == bv && i2 < bi2)) { bv = v; bi2 = i2; }
            }
            idxs[tid] = bi2;
        }
        __syncthreads();

        // update: r -= q, accumulate (r_new)^2
        float partial = 0.f;
        for (int e = tid; e < TILE * 256; e += 256) {
            const int row = e >> 8, col = e & 255;
            const float q = C[(size_t)idxs[row] * 256 + col];
            const size_t gi = (size_t)(brow + row) * 256 + col;
            const float rn = R[gi] - q;
            R[gi] = rn;
            partial = fmaf(rn, rn, partial);
        }
        __syncthreads();
        float* red = &redv[0][0];
        red[tid] = partial;
        __syncthreads();
        for (int s = 128; s > 0; s >>= 1) {
            if (tid < s) red[tid] += red[tid + s];
            __syncthreads();
        }
        if (tid == 0) atomicAdd(&lossOut[1 + stage], red[0] * lscale);
        __syncthreads();
    }
}

// ---------------------------------------------------------------------------
extern "C" void kernel_launch(void* const* d_in, const int* in_sizes, int n_in,
                              void* d_out, int out_size, void* d_ws, size_t ws_size,
                              hipStream_t stream)
{
    const float* x   = (const float*)d_in[0];
    const float* eW1 = (const float*)d_in[1];
    const float* eb1 = (const float*)d_in[2];
    const float* eW2 = (const float*)d_in[3];
    const float* eb2 = (const float*)d_in[4];
    const float* dW1 = (const float*)d_in[5];
    const float* db1 = (const float*)d_in[6];
    const float* dW2 = (const float*)d_in[7];
    const float* db2 = (const float*)d_in[8];
    const float* C0  = (const float*)d_in[9];
    const float* C1  = (const float*)d_in[10];
    const float* C2  = (const float*)d_in[11];
    float* out = (float*)d_out;

    char* ws = (char*)d_ws;
    float* H  = (float*)ws;                                   // 65536*512 f32 = 128MB (H1 then H2)
    float* Z  = (float*)(ws + (size_t)128 * 1024 * 1024);     // 64MB
    float* R  = (float*)(ws + (size_t)192 * 1024 * 1024);     // 64MB
    float* cn = (float*)(ws + (size_t)256 * 1024 * 1024);     // 1792 f32

    hipMemsetAsync(d_out, 0, 4 * sizeof(float), stream);

    cnorm_kernel<<<1024, 64, 0, stream>>>(C0, cn);
    cnorm_kernel<<<512, 64, 0, stream>>>(C1, cn + 1024);
    cnorm_kernel<<<256, 64, 0, stream>>>(C2, cn + 1536);

    const dim3 blk(256);
    // GEMM1: H = gelu(x @ eW1 + eb1)   [65536,1024]x[1024,512]
    gemm_f32<0, false><<<dim3(512 / TILE, 65536 / TILE), blk, 0, stream>>>(
        x, nullptr, eW1, eb1, H, nullptr, nullptr, nullptr, 512, 1024, 0.f);
    // GEMM2: Z = R = H @ eW2 + eb2     [65536,512]x[512,256]
    gemm_f32<1, false><<<dim3(256 / TILE, 65536 / TILE), blk, 0, stream>>>(
        H, nullptr, eW2, eb2, Z, R, nullptr, nullptr, 256, 512, 0.f);
    // VQ stages (updates R in place, adds losses to out[1..3])
    vq_kernel<<<65536 / TILE, blk, 0, stream>>>(R, C0, C1, C2, cn, out);
    // GEMM3: H = gelu((Z - R) @ dW1 + db1)   [65536,256]x[256,512]
    gemm_f32<0, true><<<dim3(512 / TILE, 65536 / TILE), blk, 0, stream>>>(
        Z, R, dW1, db1, H, nullptr, nullptr, nullptr, 512, 256, 0.f);
    // GEMM4: recon = mean((H @ dW2 + db2 - x)^2)  [65536,512]x[512,1024]
    gemm_f32<2, false><<<dim3(1024 / TILE, 65536 / TILE), blk, 0, stream>>>(
        H, nullptr, dW2, db2, nullptr, nullptr, x, out, 1024, 512,
        1.0f / (65536.0f * 1024.0f));
}

// Round 2
// 744.623 us; speedup vs baseline: 3.9213x; 3.9213x over previous
//
#include <hip/hip_runtime.h>
#include <cstddef>

// ---------------------------------------------------------------------------
// RQ-VAE forward, bf16-MFMA pipeline.
//   prep:  weights -> Wt bf16 [N][K]; codebooks -> bf16 + f32 norms
//   G1: H1 = gelu(x @ eW1 + eb1)          (A: f32->bf16 in-flight)   -> bf16
//   G2: Z  = H1 @ eW2 + eb2                                           -> f32
//   VQ: 3 stages of argmin/commit/residual (bf16 MFMA scoring,
//       f32 register residual), emits ZQ = Z - R_final as bf16
//   G3: H2 = gelu(ZQ @ dW1 + db1)                                     -> bf16
//   G4: recon = mean((H2 @ dW2 + db2 - x)^2)   (loss-only epilogue)
// ---------------------------------------------------------------------------

typedef __attribute__((ext_vector_type(8))) __bf16 bf16x8;
typedef __attribute__((ext_vector_type(4))) float f32x4;
typedef unsigned short u16;

__device__ __forceinline__ u16 f2bf(float f) {
    unsigned u = __float_as_uint(f);
    u += 0x7fffu + ((u >> 16) & 1u);      // round-to-nearest-even
    return (u16)(u >> 16);
}
__device__ __forceinline__ float gelu_exact(float v) {
    return 0.5f * v * (1.0f + erff(v * 0.7071067811865475f));
}
__device__ __forceinline__ void gload16(const void* g, void* l) {
    __builtin_amdgcn_global_load_lds(
        (const __attribute__((address_space(1))) void*)g,
        (__attribute__((address_space(3))) void*)l, 16, 0, 0);
}
__device__ __forceinline__ f32x4 mfma_bf16(bf16x8 a, bf16x8 b, f32x4 c) {
    return __builtin_amdgcn_mfma_f32_16x16x32_bf16(a, b, c, 0, 0, 0);
}

// ---------------------------------------------------------------------------
// prep: transpose+cast the 4 weights to bf16 [N][K]
__global__ __launch_bounds__(256)
void prep_weights(const float* __restrict__ eW1, const float* __restrict__ eW2,
                  const float* __restrict__ dW1, const float* __restrict__ dW2,
                  u16* __restrict__ eW1t, u16* __restrict__ eW2t,
                  u16* __restrict__ dW1t, u16* __restrict__ dW2t)
{
    const int b = blockIdx.x, t = threadIdx.x;
    if (b < 2048) {                    // eW1 [1024][512] -> [512][1024]
        int e = b * 256 + t;
        int n = e >> 10, k = e & 1023;
        eW1t[e] = f2bf(eW1[(size_t)k * 512 + n]);
    } else if (b < 2560) {             // eW2 [512][256] -> [256][512]
        int e = (b - 2048) * 256 + t;
        int n = e >> 9, k = e & 511;
        eW2t[e] = f2bf(eW2[(size_t)k * 256 + n]);
    } else if (b < 3072) {             // dW1 [256][512] -> [512][256]
        int e = (b - 2560) * 256 + t;
        int n = e >> 8, k = e & 255;
        dW1t[e] = f2bf(dW1[(size_t)k * 512 + n]);
    } else {                           // dW2 [512][1024] -> [1024][512]
        int e = (b - 3072) * 256 + t;
        int n = e >> 9, k = e & 511;
        dW2t[e] = f2bf(dW2[(size_t)k * 1024 + n]);
    }
}

// codebooks: bf16 cast (contiguous [1792][256]) + f32 squared norms
__global__ __launch_bounds__(256)
void cb_prep(const float* __restrict__ C0, const float* __restrict__ C1,
             const float* __restrict__ C2, u16* __restrict__ Cbf,
             float* __restrict__ cnorm)
{
    __shared__ float red[256];
    const int code = blockIdx.x, t = threadIdx.x;
    const float* C;
    int local;
    if (code < 1024)      { C = C0; local = code; }
    else if (code < 1536) { C = C1; local = code - 1024; }
    else                  { C = C2; local = code - 1536; }
    const float v = C[(size_t)local * 256 + t];
    Cbf[(size_t)code * 256 + t] = f2bf(v);
    red[t] = v * v;
    __syncthreads();
    for (int s = 128; s; s >>= 1) { if (t < s) red[t] += red[t + s]; __syncthreads(); }
    if (t == 0) cnorm[code] = red[0];
}

// ---------------------------------------------------------------------------
// MFMA GEMM: C = A[M,K] @ Bt[N,K]^T, 128x128 tile, BK=32, 4 waves, dbuf LDS.
// EPI: 0 = gelu -> bf16 store, 1 = plain -> f32 store, 2 = sq-err loss vs X
// AF32: A is f32, converted to bf16 during staging (reg path).
template <int EPI, bool AF32>
__global__ __launch_bounds__(256, 2)
void gemm_mfma(const void* __restrict__ Aptr, const u16* __restrict__ Bt,
               const float* __restrict__ bias, u16* __restrict__ Obf,
               float* __restrict__ Of, const float* __restrict__ X,
               float* __restrict__ lossOut, int N, int K, int ntn,
               float lossScale)
{
    __shared__ __align__(16) u16 As[2][128 * 32];
    __shared__ __align__(16) u16 Bs[2][128 * 32];

    const int nwg = gridDim.x;
    const int bid = blockIdx.x;
    const int wg  = (bid & 7) * (nwg >> 3) + (bid >> 3);   // XCD-chunked swizzle
    const int brow = (wg / ntn) * 128;
    const int bcol = (wg % ntn) * 128;

    const int t    = threadIdx.x;
    const int lane = t & 63;
    const int wid  = t >> 6;
    const int wrow = (wid >> 1) * 64, wcol = (wid & 1) * 64;
    const int lrow = lane & 15, lk8 = (lane >> 4) * 8;

    const int nt = K >> 5;   // K-steps of 32

    f32x4 acc[4][4];
#pragma unroll
    for (int m = 0; m < 4; ++m)
#pragma unroll
        for (int n = 0; n < 4; ++n) acc[m][n] = (f32x4)0.f;

    const u16*   Abf = (const u16*)Aptr;
    const float* Af  = (const float*)Aptr;

    // ---- staging helpers ----
    auto stageB = [&](int kt, int buf) {
#pragma unroll
        for (int it = 0; it < 2; ++it) {
            const int e0 = (it * 256 + t) * 8;
            const int row = e0 >> 5, col = e0 & 31;
            gload16(&Bt[(size_t)(bcol + row) * K + kt * 32 + col],
                    (char*)&Bs[buf][0] + (size_t)e0 * 2);
        }
    };
    auto stageA_bf = [&](int kt, int buf) {
#pragma unroll
        for (int it = 0; it < 2; ++it) {
            const int e0 = (it * 256 + t) * 8;
            const int row = e0 >> 5, col = e0 & 31;
            gload16(&Abf[(size_t)(brow + row) * K + kt * 32 + col],
                    (char*)&As[buf][0] + (size_t)e0 * 2);
        }
    };
    auto issueA_f32 = [&](int kt, float4* r) {
#pragma unroll
        for (int it = 0; it < 4; ++it) {
            const int e0 = (it * 256 + t) * 4;
            const int row = e0 >> 5, col = e0 & 31;
            r[it] = *(const float4*)&Af[(size_t)(brow + row) * K + kt * 32 + col];
        }
    };
    auto writeA_f32 = [&](int buf, const float4* r) {
#pragma unroll
        for (int it = 0; it < 4; ++it) {
            const int e0 = (it * 256 + t) * 4;
            const float4 v = r[it];
            unsigned lo = (unsigned)f2bf(v.x) | ((unsigned)f2bf(v.y) << 16);
            unsigned hi = (unsigned)f2bf(v.z) | ((unsigned)f2bf(v.w) << 16);
            *(uint2*)((char*)&As[buf][0] + (size_t)e0 * 2) = make_uint2(lo, hi);
        }
    };

    // ---- prologue ----
    if (AF32) {
        float4 r0[4];
        issueA_f32(0, r0);
        stageB(0, 0);
        writeA_f32(0, r0);
    } else {
        stageA_bf(0, 0);
        stageB(0, 0);
    }
    __syncthreads();

    int cur = 0;
    for (int kt = 0; kt < nt; ++kt) {
        const bool last = (kt == nt - 1);
        float4 rnext[4];
        if (!last) {
            if (AF32) issueA_f32(kt + 1, rnext);
            else      stageA_bf(kt + 1, cur ^ 1);
            stageB(kt + 1, cur ^ 1);
        }
        // compute current buffer
        bf16x8 a[4], b[4];
#pragma unroll
        for (int m = 0; m < 4; ++m)
            a[m] = *(const bf16x8*)&As[cur][(wrow + m * 16 + lrow) * 32 + lk8];
#pragma unroll
        for (int n = 0; n < 4; ++n)
            b[n] = *(const bf16x8*)&Bs[cur][(wcol + n * 16 + lrow) * 32 + lk8];
#pragma unroll
        for (int m = 0; m < 4; ++m)
#pragma unroll
            for (int n = 0; n < 4; ++n)
                acc[m][n] = mfma_bf16(a[m], b[n], acc[m][n]);

        if (AF32 && !last) writeA_f32(cur ^ 1, rnext);
        __syncthreads();
        cur ^= 1;
    }

    // ---- epilogue ----
    int   colN[4];
    float bn[4];
#pragma unroll
    for (int n = 0; n < 4; ++n) {
        colN[n] = bcol + wcol + n * 16 + lrow;
        bn[n]   = bias[colN[n]];
    }

    if (EPI == 0) {
#pragma unroll
        for (int m = 0; m < 4; ++m) {
            const int rowb = brow + wrow + m * 16 + (lane >> 4) * 4;
#pragma unroll
            for (int n = 0; n < 4; ++n)
#pragma unroll
                for (int j = 0; j < 4; ++j)
                    Obf[(size_t)(rowb + j) * N + colN[n]] =
                        f2bf(gelu_exact(acc[m][n][j] + bn[n]));
        }
    } else if (EPI == 1) {
#pragma unroll
        for (int m = 0; m < 4; ++m) {
            const int rowb = brow + wrow + m * 16 + (lane >> 4) * 4;
#pragma unroll
            for (int n = 0; n < 4; ++n)
#pragma unroll
                for (int j = 0; j < 4; ++j)
                    Of[(size_t)(rowb + j) * N + colN[n]] = acc[m][n][j] + bn[n];
        }
    } else {
        float partial = 0.f;
#pragma unroll
        for (int m = 0; m < 4; ++m) {
            const int rowb = brow + wrow + m * 16 + (lane >> 4) * 4;
#pragma unroll
            for (int n = 0; n < 4; ++n)
#pragma unroll
                for (int j = 0; j < 4; ++j) {
                    const float o = acc[m][n][j] + bn[n];
                    const float d = o - X[(size_t)(rowb + j) * N + colN[n]];
                    partial = fmaf(d, d, partial);
                }
        }
        float* red = (float*)&As[0][0];
        red[t] = partial;
        __syncthreads();
        for (int s = 128; s; s >>= 1) { if (t < s) red[t] += red[t + s]; __syncthreads(); }
        if (t == 0) atomicAdd(lossOut, red[0] * lossScale);
    }
}

// ---------------------------------------------------------------------------
// VQ: 64 rows/block, residual f32 in registers (thread t owns column t),
// bf16 LDS mirror per stage for MFMA scoring against bf16 codebooks.
__global__ __launch_bounds__(256, 2)
void vq_mfma(const float* __restrict__ Z, const u16* __restrict__ Cbf,
             const float* __restrict__ cnorm,
             const float* __restrict__ C0, const float* __restrict__ C1,
             const float* __restrict__ C2,
             u16* __restrict__ ZQ, float* __restrict__ lossOut)
{
    __shared__ __align__(16) u16 Rb[64][264];   // +8 pad: 2-way (free) banks
    __shared__ float redv[64][4];
    __shared__ int   redi[64][4];
    __shared__ int   idxs[64];
    __shared__ float lred[256];

    const int t    = threadIdx.x;
    const int lane = t & 63;
    const int wid  = t >> 6;
    const int lrow = lane & 15, g = lane >> 4;
    const int brow = blockIdx.x * 64;

    float R[64];
#pragma unroll
    for (int r = 0; r < 64; ++r) R[r] = Z[(size_t)(brow + r) * 256 + t];

    const float* Cf[3]  = {C0, C1, C2};
    const int ncodes[3] = {1024, 512, 256};
    const int coff[3]   = {0, 1024, 1536};
    const float lscale  = 1.25f / (65536.0f * 256.0f);

    for (int stage = 0; stage < 3; ++stage) {
        // 1) bf16 mirror of residual
#pragma unroll
        for (int r = 0; r < 64; ++r) Rb[r][t] = f2bf(R[r]);
        __syncthreads();

        // 2) scoring: s = ||c||^2 - 2 r.c  via MFMA (wave covers 32 codes)
        float best[4][4];
        int   bidx[4][4];
#pragma unroll
        for (int m = 0; m < 4; ++m)
#pragma unroll
            for (int j = 0; j < 4; ++j) { best[m][j] = 3.0e38f; bidx[m][j] = 0; }

        const u16*   Cb  = Cbf + (size_t)coff[stage] * 256;
        const float* cns = cnorm + coff[stage];

        for (int ct = 0; ct < ncodes[stage]; ct += 128) {
            f32x4 acc[4][2];
#pragma unroll
            for (int m = 0; m < 4; ++m)
#pragma unroll
                for (int n = 0; n < 2; ++n) acc[m][n] = (f32x4)0.f;
            const int cbase = ct + wid * 32;
#pragma unroll
            for (int ks = 0; ks < 8; ++ks) {
                const int k0 = ks * 32 + g * 8;
                bf16x8 a[4], b[2];
#pragma unroll
                for (int m = 0; m < 4; ++m)
                    a[m] = *(const bf16x8*)&Rb[m * 16 + lrow][k0];
#pragma unroll
                for (int n = 0; n < 2; ++n)
                    b[n] = *(const bf16x8*)&Cb[(size_t)(cbase + n * 16 + lrow) * 256 + k0];
#pragma unroll
                for (int n = 0; n < 2; ++n)
#pragma unroll
                    for (int m = 0; m < 4; ++m)
                        acc[m][n] = mfma_bf16(a[m], b[n], acc[m][n]);
            }
#pragma unroll
            for (int n = 0; n < 2; ++n) {
                const int code = cbase + n * 16 + lrow;
                const float cn = cns[code];
#pragma unroll
                for (int m = 0; m < 4; ++m)
#pragma unroll
                    for (int j = 0; j < 4; ++j) {
                        const float s = fmaf(-2.0f, acc[m][n][j], cn);
                        if (s < best[m][j]) { best[m][j] = s; bidx[m][j] = code; }
                    }
            }
        }

        // 3) argmin reduce: 16 lanes of each row-group, then across 4 waves
#pragma unroll
        for (int m = 0; m < 4; ++m)
#pragma unroll
            for (int j = 0; j < 4; ++j) {
                float v = best[m][j];
                int   i = bidx[m][j];
                for (int d = 1; d < 16; d <<= 1) {
                    const float ov = __shfl_xor(v, d);
                    const int   oi = __shfl_xor(i, d);
                    if (ov < v || (ov == v && oi < i)) { v = ov; i = oi; }
                }
                if (lrow == 0) {
                    redv[m * 16 + g * 4 + j][wid] = v;
                    redi[m * 16 + g * 4 + j][wid] = i;
                }
            }
        __syncthreads();
        if (t < 64) {
            float v = redv[t][0];
            int   i = redi[t][0];
#pragma unroll
            for (int w = 1; w < 4; ++w) {
                const float ov = redv[t][w];
                const int   oi = redi[t][w];
                if (ov < v || (ov == v && oi < i)) { v = ov; i = oi; }
            }
            idxs[t] = i;
        }
        __syncthreads();

        // 4) residual update + commit loss (f32, thread owns column t)
        const float* Cfs = Cf[stage];
        float partial = 0.f;
#pragma unroll
        for (int r = 0; r < 64; ++r) {
            const float q  = Cfs[(size_t)idxs[r] * 256 + t];
            const float rn = R[r] - q;
            R[r] = rn;
            partial = fmaf(rn, rn, partial);
        }
        lred[t] = partial;
        __syncthreads();
        for (int s = 128; s; s >>= 1) { if (t < s) lred[t] += lred[t + s]; __syncthreads(); }
        if (t == 0) atomicAdd(&lossOut[1 + stage], lred[0] * lscale);
        __syncthreads();
    }

    // 5) ZQ = Z - R_final  (== sum of selected codes), bf16
#pragma unroll
    for (int r = 0; r < 64; ++r) {
        const float zq = Z[(size_t)(brow + r) * 256 + t] - R[r];
        ZQ[(size_t)(brow + r) * 256 + t] = f2bf(zq);
    }
}

// ---------------------------------------------------------------------------
extern "C" void kernel_launch(void* const* d_in, const int* in_sizes, int n_in,
                              void* d_out, int out_size, void* d_ws, size_t ws_size,
                              hipStream_t stream)
{
    const float* x   = (const float*)d_in[0];
    const float* eW1 = (const float*)d_in[1];
    const float* eb1 = (const float*)d_in[2];
    const float* eW2 = (const float*)d_in[3];
    const float* eb2 = (const float*)d_in[4];
    const float* dW1 = (const float*)d_in[5];
    const float* db1 = (const float*)d_in[6];
    const float* dW2 = (const float*)d_in[7];
    const float* db2 = (const float*)d_in[8];
    const float* C0  = (const float*)d_in[9];
    const float* C1  = (const float*)d_in[10];
    const float* C2  = (const float*)d_in[11];
    float* out = (float*)d_out;

    char* w = (char*)d_ws;
    u16*   H1   = (u16*)(w);                          // 64 MiB
    float* Zf   = (float*)(w + ((size_t)64 << 20));   // 64 MiB
    u16*   ZQ   = (u16*)(w + ((size_t)128 << 20));    // 32 MiB
    u16*   H2   = (u16*)(w + ((size_t)160 << 20));    // 64 MiB
    u16*   eW1t = (u16*)(w + ((size_t)224 << 20));
    u16*   eW2t = (u16*)(w + ((size_t)225 << 20));
    u16*   dW1t = (u16*)(w + ((size_t)226 << 20));
    u16*   dW2t = (u16*)(w + ((size_t)227 << 20));
    u16*   Cbf  = (u16*)(w + ((size_t)228 << 20));
    float* cn   = (float*)(w + ((size_t)229 << 20));

    hipMemsetAsync(d_out, 0, 4 * sizeof(float), stream);

    prep_weights<<<5120, 256, 0, stream>>>(eW1, eW2, dW1, dW2, eW1t, eW2t, dW1t, dW2t);
    cb_prep<<<1792, 256, 0, stream>>>(C0, C1, C2, Cbf, cn);

    // G1: H1 = gelu(x @ eW1 + eb1)    M=65536 N=512 K=1024, A f32
    gemm_mfma<0, true><<<2048, 256, 0, stream>>>(
        x, eW1t, eb1, H1, nullptr, nullptr, nullptr, 512, 1024, 4, 0.f);
    // G2: Z = H1 @ eW2 + eb2          M=65536 N=256 K=512
    gemm_mfma<1, false><<<1024, 256, 0, stream>>>(
        H1, eW2t, eb2, nullptr, Zf, nullptr, nullptr, 256, 512, 2, 0.f);
    // VQ: 3 stages, emits ZQ bf16 + losses[1..3]
    vq_mfma<<<1024, 256, 0, stream>>>(Zf, Cbf, cn, C0, C1, C2, ZQ, out);
    // G3: H2 = gelu(ZQ @ dW1 + db1)   M=65536 N=512 K=256
    gemm_mfma<0, false><<<2048, 256, 0, stream>>>(
        ZQ, dW1t, db1, H2, nullptr, nullptr, nullptr, 512, 256, 4, 0.f);
    // G4: recon loss                  M=65536 N=1024 K=512
    gemm_mfma<2, false><<<4096, 256, 0, stream>>>(
        H2, dW2t, db2, nullptr, nullptr, x, out, 1024, 512, 8,
        1.0f / (65536.0f * 1024.0f));
}

// Round 3
// 673.296 us; speedup vs baseline: 4.3367x; 1.1059x over previous
//
#include <hip/hip_runtime.h>
#include <cstddef>

// ---------------------------------------------------------------------------
// RQ-VAE forward, bf16-MFMA pipeline.
//   prep:  weights -> Wt bf16 [N][K]; codebooks -> bf16 + f32 norms
//   G1: H1 = gelu(x @ eW1 + eb1)          (A: f32->bf16 in-flight)   -> bf16
//   G2: Z  = H1 @ eW2 + eb2                                           -> f32
//   VQ: 3 stages (wave-owned rows, reg A-frags, LDS-staged codebook),
//       f32 register residual; emits ZQ = q0+q1+q2 as bf16
//   G3: H2 = gelu(ZQ @ dW1 + db1)                                     -> bf16
//   G4: recon = mean((H2 @ dW2 + db2 - x)^2)   (loss-only epilogue)
// ---------------------------------------------------------------------------

typedef __attribute__((ext_vector_type(8))) __bf16 bf16x8;
typedef __attribute__((ext_vector_type(4))) float f32x4;
typedef unsigned short u16;

__device__ __forceinline__ u16 f2bf(float f) {
    unsigned u = __float_as_uint(f);
    u += 0x7fffu + ((u >> 16) & 1u);      // round-to-nearest-even
    return (u16)(u >> 16);
}
__device__ __forceinline__ float gelu_exact(float v) {
    return 0.5f * v * (1.0f + erff(v * 0.7071067811865475f));
}
__device__ __forceinline__ void gload16(const void* g, void* l) {
    __builtin_amdgcn_global_load_lds(
        (const __attribute__((address_space(1))) void*)g,
        (__attribute__((address_space(3))) void*)l, 16, 0, 0);
}
__device__ __forceinline__ f32x4 mfma_bf16(bf16x8 a, bf16x8 b, f32x4 c) {
    return __builtin_amdgcn_mfma_f32_16x16x32_bf16(a, b, c, 0, 0, 0);
}

// ---------------------------------------------------------------------------
// prep: transpose+cast the 4 weights to bf16 [N][K]
__global__ __launch_bounds__(256)
void prep_weights(const float* __restrict__ eW1, const float* __restrict__ eW2,
                  const float* __restrict__ dW1, const float* __restrict__ dW2,
                  u16* __restrict__ eW1t, u16* __restrict__ eW2t,
                  u16* __restrict__ dW1t, u16* __restrict__ dW2t)
{
    const int b = blockIdx.x, t = threadIdx.x;
    if (b < 2048) {                    // eW1 [1024][512] -> [512][1024]
        int e = b * 256 + t;
        int n = e >> 10, k = e & 1023;
        eW1t[e] = f2bf(eW1[(size_t)k * 512 + n]);
    } else if (b < 2560) {             // eW2 [512][256] -> [256][512]
        int e = (b - 2048) * 256 + t;
        int n = e >> 9, k = e & 511;
        eW2t[e] = f2bf(eW2[(size_t)k * 256 + n]);
    } else if (b < 3072) {             // dW1 [256][512] -> [512][256]
        int e = (b - 2560) * 256 + t;
        int n = e >> 8, k = e & 255;
        dW1t[e] = f2bf(dW1[(size_t)k * 512 + n]);
    } else {                           // dW2 [512][1024] -> [1024][512]
        int e = (b - 3072) * 256 + t;
        int n = e >> 9, k = e & 511;
        dW2t[e] = f2bf(dW2[(size_t)k * 1024 + n]);
    }
}

// codebooks: bf16 cast (contiguous [1792][256]) + f32 squared norms
__global__ __launch_bounds__(256)
void cb_prep(const float* __restrict__ C0, const float* __restrict__ C1,
             const float* __restrict__ C2, u16* __restrict__ Cbf,
             float* __restrict__ cnorm)
{
    __shared__ float red[256];
    const int code = blockIdx.x, t = threadIdx.x;
    const float* C;
    int local;
    if (code < 1024)      { C = C0; local = code; }
    else if (code < 1536) { C = C1; local = code - 1024; }
    else                  { C = C2; local = code - 1536; }
    const float v = C[(size_t)local * 256 + t];
    Cbf[(size_t)code * 256 + t] = f2bf(v);
    red[t] = v * v;
    __syncthreads();
    for (int s = 128; s; s >>= 1) { if (t < s) red[t] += red[t + s]; __syncthreads(); }
    if (t == 0) cnorm[code] = red[0];
}

// ---------------------------------------------------------------------------
// MFMA GEMM: C = A[M,K] @ Bt[N,K]^T, 128x128 tile, BK=32, 4 waves, dbuf LDS.
// EPI: 0 = gelu -> bf16 store, 1 = plain -> f32 store, 2 = sq-err loss vs X
// AF32: A is f32, converted to bf16 during staging (reg path).
template <int EPI, bool AF32>
__global__ __launch_bounds__(256, 2)
void gemm_mfma(const void* __restrict__ Aptr, const u16* __restrict__ Bt,
               const float* __restrict__ bias, u16* __restrict__ Obf,
               float* __restrict__ Of, const float* __restrict__ X,
               float* __restrict__ lossOut, int N, int K, int ntn,
               float lossScale)
{
    __shared__ __align__(16) u16 As[2][128 * 32];
    __shared__ __align__(16) u16 Bs[2][128 * 32];

    const int nwg = gridDim.x;
    const int bid = blockIdx.x;
    const int wg  = (bid & 7) * (nwg >> 3) + (bid >> 3);   // XCD-chunked swizzle
    const int brow = (wg / ntn) * 128;
    const int bcol = (wg % ntn) * 128;

    const int t    = threadIdx.x;
    const int lane = t & 63;
    const int wid  = t >> 6;
    const int wrow = (wid >> 1) * 64, wcol = (wid & 1) * 64;
    const int lrow = lane & 15, lk8 = (lane >> 4) * 8;

    const int nt = K >> 5;   // K-steps of 32

    f32x4 acc[4][4];
#pragma unroll
    for (int m = 0; m < 4; ++m)
#pragma unroll
        for (int n = 0; n < 4; ++n) acc[m][n] = (f32x4)0.f;

    const u16*   Abf = (const u16*)Aptr;
    const float* Af  = (const float*)Aptr;

    // ---- staging helpers ----
    auto stageB = [&](int kt, int buf) {
#pragma unroll
        for (int it = 0; it < 2; ++it) {
            const int e0 = (it * 256 + t) * 8;
            const int row = e0 >> 5, col = e0 & 31;
            gload16(&Bt[(size_t)(bcol + row) * K + kt * 32 + col],
                    (char*)&Bs[buf][0] + (size_t)e0 * 2);
        }
    };
    auto stageA_bf = [&](int kt, int buf) {
#pragma unroll
        for (int it = 0; it < 2; ++it) {
            const int e0 = (it * 256 + t) * 8;
            const int row = e0 >> 5, col = e0 & 31;
            gload16(&Abf[(size_t)(brow + row) * K + kt * 32 + col],
                    (char*)&As[buf][0] + (size_t)e0 * 2);
        }
    };
    auto issueA_f32 = [&](int kt, float4* r) {
#pragma unroll
        for (int it = 0; it < 4; ++it) {
            const int e0 = (it * 256 + t) * 4;
            const int row = e0 >> 5, col = e0 & 31;
            r[it] = *(const float4*)&Af[(size_t)(brow + row) * K + kt * 32 + col];
        }
    };
    auto writeA_f32 = [&](int buf, const float4* r) {
#pragma unroll
        for (int it = 0; it < 4; ++it) {
            const int e0 = (it * 256 + t) * 4;
            const float4 v = r[it];
            unsigned lo = (unsigned)f2bf(v.x) | ((unsigned)f2bf(v.y) << 16);
            unsigned hi = (unsigned)f2bf(v.z) | ((unsigned)f2bf(v.w) << 16);
            *(uint2*)((char*)&As[buf][0] + (size_t)e0 * 2) = make_uint2(lo, hi);
        }
    };

    // ---- prologue ----
    if (AF32) {
        float4 r0[4];
        issueA_f32(0, r0);
        stageB(0, 0);
        writeA_f32(0, r0);
    } else {
        stageA_bf(0, 0);
        stageB(0, 0);
    }
    __syncthreads();

    int cur = 0;
    for (int kt = 0; kt < nt; ++kt) {
        const bool last = (kt == nt - 1);
        float4 rnext[4];
        if (!last) {
            if (AF32) issueA_f32(kt + 1, rnext);
            else      stageA_bf(kt + 1, cur ^ 1);
            stageB(kt + 1, cur ^ 1);
        }
        // compute current buffer
        bf16x8 a[4], b[4];
#pragma unroll
        for (int m = 0; m < 4; ++m)
            a[m] = *(const bf16x8*)&As[cur][(wrow + m * 16 + lrow) * 32 + lk8];
#pragma unroll
        for (int n = 0; n < 4; ++n)
            b[n] = *(const bf16x8*)&Bs[cur][(wcol + n * 16 + lrow) * 32 + lk8];
#pragma unroll
        for (int m = 0; m < 4; ++m)
#pragma unroll
            for (int n = 0; n < 4; ++n)
                acc[m][n] = mfma_bf16(a[m], b[n], acc[m][n]);

        if (AF32 && !last) writeA_f32(cur ^ 1, rnext);
        __syncthreads();
        cur ^= 1;
    }

    // ---- epilogue ----
    int   colN[4];
    float bn[4];
#pragma unroll
    for (int n = 0; n < 4; ++n) {
        colN[n] = bcol + wcol + n * 16 + lrow;
        bn[n]   = bias[colN[n]];
    }

    if (EPI == 0) {
#pragma unroll
        for (int m = 0; m < 4; ++m) {
            const int rowb = brow + wrow + m * 16 + (lane >> 4) * 4;
#pragma unroll
            for (int n = 0; n < 4; ++n)
#pragma unroll
                for (int j = 0; j < 4; ++j)
                    Obf[(size_t)(rowb + j) * N + colN[n]] =
                        f2bf(gelu_exact(acc[m][n][j] + bn[n]));
        }
    } else if (EPI == 1) {
#pragma unroll
        for (int m = 0; m < 4; ++m) {
            const int rowb = brow + wrow + m * 16 + (lane >> 4) * 4;
#pragma unroll
            for (int n = 0; n < 4; ++n)
#pragma unroll
                for (int j = 0; j < 4; ++j)
                    Of[(size_t)(rowb + j) * N + colN[n]] = acc[m][n][j] + bn[n];
        }
    } else {
        float partial = 0.f;
#pragma unroll
        for (int m = 0; m < 4; ++m) {
            const int rowb = brow + wrow + m * 16 + (lane >> 4) * 4;
#pragma unroll
            for (int n = 0; n < 4; ++n)
#pragma unroll
                for (int j = 0; j < 4; ++j) {
                    const float o = acc[m][n][j] + bn[n];
                    const float d = o - X[(size_t)(rowb + j) * N + colN[n]];
                    partial = fmaf(d, d, partial);
                }
        }
        float* red = (float*)&As[0][0];
        red[t] = partial;
        __syncthreads();
        for (int s = 128; s; s >>= 1) { if (t < s) red[t] += red[t + s]; __syncthreads(); }
        if (t == 0) atomicAdd(lossOut, red[0] * lossScale);
    }
}

// ---------------------------------------------------------------------------
// VQ v3: 64 rows/block (4 waves x 16 rows). Residual f32 in registers
// (thread t owns column t). Per stage:
//   - bf16 mirror of R into LDS, each wave loads its 16-row A-frags to regs
//   - codebook scored from double-buffered, XOR-swizzled LDS tiles
//     (32 codes x 128 k halves, global_load_lds staged, 2-phase pipeline)
//   - wave-local argmin (rows are wave-exclusive), f32 residual update + loss
// Final: ZQ = C0[i0]+C1[i1]+C2[i2] (no Z re-read).
__global__ __launch_bounds__(256, 3)
void vq_mfma(const float* __restrict__ Z, const u16* __restrict__ Cbf,
             const float* __restrict__ cnorm,
             const float* __restrict__ C0, const float* __restrict__ C1,
             const float* __restrict__ C2,
             u16* __restrict__ ZQ, float* __restrict__ lossOut)
{
    __shared__ __align__(16) u16 Rb[64][264];     // 16B-aligned rows, ~2-way banks
    __shared__ __align__(16) u16 Cs[2][4096];     // 2 x (32 codes x 128 k), swizzled
    __shared__ int   idxs[3][64];
    __shared__ float lred[256];

    const int t    = threadIdx.x;
    const int lane = t & 63;
    const int wid  = t >> 6;
    const int lrow = lane & 15, g = lane >> 4;
    const int brow = blockIdx.x * 64;

    float R[64];
#pragma unroll
    for (int r = 0; r < 64; ++r) R[r] = Z[(size_t)(brow + r) * 256 + t];

    const float* Cf[3]  = {C0, C1, C2};
    const int ncodes[3] = {1024, 512, 256};
    const int coff[3]   = {0, 1024, 1536};
    const float lscale  = 1.25f / (65536.0f * 256.0f);

#pragma unroll
    for (int stage = 0; stage < 3; ++stage) {
        const u16*   Cb  = Cbf + (size_t)coff[stage] * 256;
        const float* cns = cnorm + coff[stage];
        const int ntiles = ncodes[stage] >> 5;

        // stage a (32-code x 128-k) half-tile into Cs[buf]; LDS dest is linear
        // (gload_lds), so the XOR swizzle is applied on the GLOBAL source and
        // mirrored on the ds_read side (both-sides rule).
        auto stageC = [&](int tile, int kh, int buf) {
#pragma unroll
            for (int it = 0; it < 2; ++it) {
                const int d   = (it * 256 + t) * 16;   // dest byte in 8KB buffer
                const int row = d >> 8;                // 0..31
                const int kb  = d & 255;
                const int kbs = kb ^ ((row & 7) << 4);
                gload16(&Cb[(size_t)(tile * 32 + row) * 256 + kh * 128 + (kbs >> 1)],
                        (char*)&Cs[buf][0] + d);
            }
        };

        stageC(0, 0, 0);                 // overlap first staging with mirror
        // bf16 mirror of residual (thread t writes column t)
#pragma unroll
        for (int r = 0; r < 64; ++r) Rb[r][t] = f2bf(R[r]);
        __syncthreads();

        // wave's 16 rows -> A fragments in registers for the whole stage
        bf16x8 a[8];
#pragma unroll
        for (int ks = 0; ks < 8; ++ks)
            a[ks] = *(const bf16x8*)&Rb[wid * 16 + lrow][ks * 32 + g * 8];

        float best[4]; int bidx[4];
#pragma unroll
        for (int j = 0; j < 4; ++j) { best[j] = 3.0e38f; bidx[j] = 0; }

#pragma unroll 1
        for (int tile = 0; tile < ntiles; ++tile) {
            f32x4 acc[2];
            acc[0] = (f32x4)0.f; acc[1] = (f32x4)0.f;

            // ---- phase 0: compute k-half 0 from Cs[0], stage k-half 1 ----
            stageC(tile, 1, 1);
            const float cn0 = cns[tile * 32 + lrow];        // early-loaded,
            const float cn1 = cns[tile * 32 + 16 + lrow];   // used in phase 1
#pragma unroll
            for (int ks2 = 0; ks2 < 4; ++ks2)
#pragma unroll
                for (int n = 0; n < 2; ++n) {
                    const int row = n * 16 + lrow;
                    const int kb2 = ks2 * 64 + g * 16;
                    bf16x8 b = *(const bf16x8*)((const char*)&Cs[0][0]
                                 + row * 256 + (kb2 ^ ((row & 7) << 4)));
                    acc[n] = mfma_bf16(a[ks2], b, acc[n]);
                }
            __syncthreads();

            // ---- phase 1: compute k-half 1 from Cs[1], stage next tile ----
            if (tile + 1 < ntiles) stageC(tile + 1, 0, 0);
#pragma unroll
            for (int ks2 = 0; ks2 < 4; ++ks2)
#pragma unroll
                for (int n = 0; n < 2; ++n) {
                    const int row = n * 16 + lrow;
                    const int kb2 = ks2 * 64 + g * 16;
                    bf16x8 b = *(const bf16x8*)((const char*)&Cs[1][0]
                                 + row * 256 + (kb2 ^ ((row & 7) << 4)));
                    acc[n] = mfma_bf16(a[4 + ks2], b, acc[n]);
                }
            // argmin epilogue (n=0 before n=1 keeps first-min tie order)
#pragma unroll
            for (int n = 0; n < 2; ++n) {
                const int code = tile * 32 + n * 16 + lrow;
                const float cn = n ? cn1 : cn0;
#pragma unroll
                for (int j = 0; j < 4; ++j) {
                    const float s = fmaf(-2.0f, acc[n][j], cn);
                    if (s < best[j]) { best[j] = s; bidx[j] = code; }
                }
            }
            __syncthreads();
        }

        // wave-local argmin across the 16 code-lanes of each row group
#pragma unroll
        for (int j = 0; j < 4; ++j) {
            float v = best[j]; int i = bidx[j];
#pragma unroll
            for (int d = 1; d < 16; d <<= 1) {
                const float ov = __shfl_xor(v, d);
                const int   oi = __shfl_xor(i, d);
                if (ov < v || (ov == v && oi < i)) { v = ov; i = oi; }
            }
            if (lrow == 0) idxs[stage][wid * 16 + g * 4 + j] = i;
        }
        __syncthreads();

        // residual update + commit loss (f32, thread owns column t)
        const float* Cfs = Cf[stage];
        float partial = 0.f;
#pragma unroll
        for (int r = 0; r < 64; ++r) {
            const float q  = Cfs[(size_t)idxs[stage][r] * 256 + t];
            const float rn = R[r] - q;
            R[r] = rn;
            partial = fmaf(rn, rn, partial);
        }
        lred[t] = partial;
        __syncthreads();
        for (int s = 128; s; s >>= 1) { if (t < s) lred[t] += lred[t + s]; __syncthreads(); }
        if (t == 0) atomicAdd(&lossOut[1 + stage], lred[0] * lscale);
        __syncthreads();
    }

    // ZQ = q0 + q1 + q2 (f32 gather from L2-resident codebooks), bf16 store
#pragma unroll
    for (int r = 0; r < 64; ++r) {
        const float zq = C0[(size_t)idxs[0][r] * 256 + t]
                       + C1[(size_t)idxs[1][r] * 256 + t]
                       + C2[(size_t)idxs[2][r] * 256 + t];
        ZQ[(size_t)(brow + r) * 256 + t] = f2bf(zq);
    }
}

// ---------------------------------------------------------------------------
extern "C" void kernel_launch(void* const* d_in, const int* in_sizes, int n_in,
                              void* d_out, int out_size, void* d_ws, size_t ws_size,
                              hipStream_t stream)
{
    const float* x   = (const float*)d_in[0];
    const float* eW1 = (const float*)d_in[1];
    const float* eb1 = (const float*)d_in[2];
    const float* eW2 = (const float*)d_in[3];
    const float* eb2 = (const float*)d_in[4];
    const float* dW1 = (const float*)d_in[5];
    const float* db1 = (const float*)d_in[6];
    const float* dW2 = (const float*)d_in[7];
    const float* db2 = (const float*)d_in[8];
    const float* C0  = (const float*)d_in[9];
    const float* C1  = (const float*)d_in[10];
    const float* C2  = (const float*)d_in[11];
    float* out = (float*)d_out;

    char* w = (char*)d_ws;
    u16*   H1   = (u16*)(w);                          // 64 MiB
    float* Zf   = (float*)(w + ((size_t)64 << 20));   // 64 MiB
    u16*   ZQ   = (u16*)(w + ((size_t)128 << 20));    // 32 MiB
    u16*   H2   = (u16*)(w + ((size_t)160 << 20));    // 64 MiB
    u16*   eW1t = (u16*)(w + ((size_t)224 << 20));
    u16*   eW2t = (u16*)(w + ((size_t)225 << 20));
    u16*   dW1t = (u16*)(w + ((size_t)226 << 20));
    u16*   dW2t = (u16*)(w + ((size_t)227 << 20));
    u16*   Cbf  = (u16*)(w + ((size_t)228 << 20));
    float* cn   = (float*)(w + ((size_t)229 << 20));

    hipMemsetAsync(d_out, 0, 4 * sizeof(float), stream);

    prep_weights<<<5120, 256, 0, stream>>>(eW1, eW2, dW1, dW2, eW1t, eW2t, dW1t, dW2t);
    cb_prep<<<1792, 256, 0, stream>>>(C0, C1, C2, Cbf, cn);

    // G1: H1 = gelu(x @ eW1 + eb1)    M=65536 N=512 K=1024, A f32
    gemm_mfma<0, true><<<2048, 256, 0, stream>>>(
        x, eW1t, eb1, H1, nullptr, nullptr, nullptr, 512, 1024, 4, 0.f);
    // G2: Z = H1 @ eW2 + eb2          M=65536 N=256 K=512
    gemm_mfma<1, false><<<1024, 256, 0, stream>>>(
        H1, eW2t, eb2, nullptr, Zf, nullptr, nullptr, 256, 512, 2, 0.f);
    // VQ: 3 stages, emits ZQ bf16 + losses[1..3]
    vq_mfma<<<1024, 256, 0, stream>>>(Zf, Cbf, cn, C0, C1, C2, ZQ, out);
    // G3: H2 = gelu(ZQ @ dW1 + db1)   M=65536 N=512 K=256
    gemm_mfma<0, false><<<2048, 256, 0, stream>>>(
        ZQ, dW1t, db1, H2, nullptr, nullptr, nullptr, 512, 256, 4, 0.f);
    // G4: recon loss                  M=65536 N=1024 K=512
    gemm_mfma<2, false><<<4096, 256, 0, stream>>>(
        H2, dW2t, db2, nullptr, nullptr, x, out, 1024, 512, 8,
        1.0f / (65536.0f * 1024.0f));
}